// Round 4
// baseline (311.780 us; speedup 1.0000x reference)
//
#include <hip/hip_runtime.h>

#define NN 2048
#define EPS 0.01f
#define ROWS 8            // rows of W per block
#define BLOCKS_PER_B 256  // 2048 / 8
#define NBLK (8 * BLOCKS_PER_B)  // 2048 blocks

typedef float f32x4 __attribute__((ext_vector_type(4)));

// Stage 1, sustained-stream shape (H1 discriminator):
// Rounds 2/3 issued one burst of loads then waited (null across 2x
// occupancy and 2x burst depth). This version software-pipelines the W
// stream: 4 chunks of 2 rows, prefetch chunk c+1 while consuming chunk c,
// so each wave issues loads continuously across its lifetime like the
// 6.3 TB/s copy ubench does. nt loads kept (proven +16 us). 32 waves/CU
// via __launch_bounds__(256, 8). Steady state: 8 float4 loads in flight.
__global__ __launch_bounds__(256, 8) void coloring_loss_stage1(
    const float* __restrict__ W,
    const float* __restrict__ pred,
    float* __restrict__ partial)
{
    __shared__ float s_partial[4];  // 4 waves

    const int bid  = blockIdx.x;
    const int b    = bid >> 8;               // bid / 256
    const int row0 = (bid & 255) * ROWS;     // first row this block owns
    const int t    = threadIdx.x;

    const float* predb = pred + (size_t)b * NN;

    // This thread's 8 comparand pred_j values -> registers (cached loads:
    // 8 KB/batch, reused by 256 blocks -> L2/L3 hits after first touch).
    const f32x4 pj0 = ((const f32x4*)predb)[t];
    const f32x4 pj1 = ((const f32x4*)predb)[t + 256];

    // Row-anchor pred_i values: block-uniform -> SGPRs.
    float pis[ROWS];
#pragma unroll
    for (int r = 0; r < ROWS; ++r)
        pis[r] = __uint_as_float(
            __builtin_amdgcn_readfirstlane(__float_as_uint(predb[row0 + r])));

    // W[b, 1, row0, :] base.
    const float* wbase = W + (((size_t)b * 2 + 1) * (size_t)NN + (size_t)row0) * (size_t)NN;

    // --- pipelined stream: 4 chunks x 2 rows x 2 f32x4 ---
    f32x4 ca[2], cb[2];   // current chunk's loads (rows 2c, 2c+1)
    f32x4 na[2], nb[2];   // next chunk's loads

    // prime chunk 0
    {
        const f32x4* r0 = (const f32x4*)(wbase + (size_t)0 * NN);
        const f32x4* r1 = (const f32x4*)(wbase + (size_t)1 * NN);
        ca[0] = __builtin_nontemporal_load(r0 + t);
        cb[0] = __builtin_nontemporal_load(r0 + t + 256);
        ca[1] = __builtin_nontemporal_load(r1 + t);
        cb[1] = __builtin_nontemporal_load(r1 + t + 256);
    }

    int cnt = 0;
#pragma unroll
    for (int c = 0; c < 4; ++c) {
        // prefetch chunk c+1 while chunk c's data is being consumed
        if (c < 3) {
            const f32x4* r0 = (const f32x4*)(wbase + (size_t)(2 * c + 2) * NN);
            const f32x4* r1 = (const f32x4*)(wbase + (size_t)(2 * c + 3) * NN);
            na[0] = __builtin_nontemporal_load(r0 + t);
            nb[0] = __builtin_nontemporal_load(r0 + t + 256);
            na[1] = __builtin_nontemporal_load(r1 + t);
            nb[1] = __builtin_nontemporal_load(r1 + t + 256);
        }
        // consume chunk c
#pragma unroll
        for (int r = 0; r < 2; ++r) {
            const float pi = pis[2 * c + r];
            const f32x4 a = ca[r];
            const f32x4 d = cb[r];
            cnt += (a.x == 1.0f) && (fabsf(pi - pj0.x) < EPS);
            cnt += (a.y == 1.0f) && (fabsf(pi - pj0.y) < EPS);
            cnt += (a.z == 1.0f) && (fabsf(pi - pj0.z) < EPS);
            cnt += (a.w == 1.0f) && (fabsf(pi - pj0.w) < EPS);
            cnt += (d.x == 1.0f) && (fabsf(pi - pj1.x) < EPS);
            cnt += (d.y == 1.0f) && (fabsf(pi - pj1.y) < EPS);
            cnt += (d.z == 1.0f) && (fabsf(pi - pj1.z) < EPS);
            cnt += (d.w == 1.0f) && (fabsf(pi - pj1.w) < EPS);
        }
        // rotate pipeline registers
#pragma unroll
        for (int r = 0; r < 2; ++r) {
            ca[r] = na[r];
            cb[r] = nb[r];
        }
    }

    // Wave (64-lane) shuffle reduction.
#pragma unroll
    for (int off = 32; off > 0; off >>= 1)
        cnt += __shfl_down(cnt, off, 64);

    const int wave = t >> 6;
    const int lane = t & 63;
    if (lane == 0) s_partial[wave] = (float)cnt;
    __syncthreads();

    if (t == 0) {
        partial[bid] = s_partial[0] + s_partial[1] + s_partial[2] + s_partial[3];
    }
}

// Stage 2: one block reduces the 2048 partials -> out[0]. Overwrites out
// unconditionally (d_out is poisoned 0xAA before every timed launch).
__global__ __launch_bounds__(256) void coloring_loss_stage2(
    const float* __restrict__ partial,
    float* __restrict__ out)
{
    __shared__ float s_partial[4];
    const int t = threadIdx.x;

    const f32x4* p4 = (const f32x4*)partial;  // 2048 floats = 512 float4
    const f32x4 a = p4[t];
    const f32x4 c = p4[t + 256];
    float s = a.x + a.y + a.z + a.w + c.x + c.y + c.z + c.w;

#pragma unroll
    for (int off = 32; off > 0; off >>= 1)
        s += __shfl_down(s, off, 64);

    const int wave = t >> 6;
    const int lane = t & 63;
    if (lane == 0) s_partial[wave] = s;
    __syncthreads();

    if (t == 0)
        out[0] = s_partial[0] + s_partial[1] + s_partial[2] + s_partial[3];
}

extern "C" void kernel_launch(void* const* d_in, const int* in_sizes, int n_in,
                              void* d_out, int out_size, void* d_ws, size_t ws_size,
                              hipStream_t stream) {
    const float* W    = (const float*)d_in[0];  // (8, 2, 2048, 2048) f32
    const float* pred = (const float*)d_in[1];  // (8, 2048) f32
    // d_in[2] (tgt) unused by the loss.
    float* out     = (float*)d_out;
    float* partial = (float*)d_ws;  // 2048 floats of scratch

    coloring_loss_stage1<<<NBLK, 256, 0, stream>>>(W, pred, partial);
    coloring_loss_stage2<<<1, 256, 0, stream>>>(partial, out);
}